// Round 4
// baseline (1829.614 us; speedup 1.0000x reference)
//
#include <hip/hip_runtime.h>

#define Bn    8
#define Cn    64
#define Hn    128
#define Wn    128
#define KK    9
#define OffC  18
#define NG    4
#define Cg    16
#define HW    (Hn*Wn)
#define CSPLIT 4
#define CCH   (Cn/CSPLIT)   // 16 input channels per wave-quarter

#define OFFS_ELEMS (Bn*OffC*HW)    // 2359296 floats
#define WT2_ELEMS  (Cn*KK*OffC)    // 10368
#define WT_ELEMS   (NG*KK*Cg*Cg)   // 2304

// ---------- Kernel 0: transpose weights into contraction-friendly layouts ----------
// wt2[ci][k][o] (o contiguous, 18)   from offw[o][ci][ky][kx]
// wt [g][k][c][o] (o contiguous, 16) from dw[g*16+o][c][ky][kx]
__global__ __launch_bounds__(256) void transpose_w_kernel(
    const float* __restrict__ offw, const float* __restrict__ dw,
    float* __restrict__ wt2, float* __restrict__ wt)
{
    const int tid = blockIdx.x * 256 + threadIdx.x;
    const int nth = gridDim.x * 256;
    for (int i = tid; i < WT2_ELEMS; i += nth) {
        const int o  = i % OffC;
        const int k  = (i / OffC) % KK;
        const int ci = i / (OffC * KK);
        wt2[i] = offw[(o * Cn + ci) * KK + k];
    }
    for (int i = tid; i < WT_ELEMS; i += nth) {
        const int o = i % Cg;
        const int c = (i / Cg) % Cg;
        const int k = (i / (Cg * Cg)) % KK;
        const int g = i / (Cg * Cg * KK);
        wt[i] = dw[((g * Cg + o) * Cg + c) * KK + k];
    }
}

// ---------- Kernel 1: offset conv (3x3, 64->18, pad 1) ----------
// Block: 64 px (half a row) x 4 ci-quarters; LDS cross-wave reduce; no atomics.
// Weights via uniform global pointer -> s_load broadcast.
__global__ __launch_bounds__(256, 8) void offset_conv_kernel(
    const float* __restrict__ x, const float* __restrict__ wt2,
    const float* __restrict__ bias, float* __restrict__ offs)
{
    __shared__ float red[CSPLIT][64][OffC + 1];   // stride 19: conflict-free
    const int tid = threadIdx.x;
    const int q   = tid >> 6;        // ci-quarter 0..3
    const int lpx = tid & 63;
    const int bid = blockIdx.x;      // b*256 + row*2 + half
    const int b   = bid >> 8;
    const int row = (bid & 255) >> 1;
    const int half= bid & 1;
    const int col = (half << 6) + lpx;

    float acc[OffC];
#pragma unroll
    for (int o = 0; o < OffC; o++) acc[o] = 0.f;

    const float* xb = x + ((size_t)b * Cn + q * CCH) * HW;
    const float* wq = wt2 + (q * CCH) * (KK * OffC);

#pragma unroll 2
    for (int ci = 0; ci < CCH; ++ci) {
        const float* xc = xb + ci * HW;
        float v[3][3];
#pragma unroll
        for (int r = 0; r < 3; ++r) {
            const int  y   = row - 1 + r;
            const bool yok = ((unsigned)y < (unsigned)Hn);
#pragma unroll
            for (int j = 0; j < 3; ++j) {
                const int xx = col - 1 + j;
                v[r][j] = (yok && (unsigned)xx < (unsigned)Wn) ? xc[y * Wn + xx] : 0.f;
            }
        }
        const float* wc = wq + ci * (KK * OffC);
#pragma unroll
        for (int t = 0; t < KK; ++t) {
            const float vv = v[t / 3][t % 3];
            const float* wk = wc + t * OffC;     // uniform -> s_load
#pragma unroll
            for (int o = 0; o < OffC; o++) acc[o] += vv * wk[o];
        }
    }

#pragma unroll
    for (int o = 0; o < OffC; o++) red[q][lpx][o] = acc[o];
    __syncthreads();

    for (int i = tid; i < 64 * OffC; i += 256) {
        const int o  = i >> 6;
        const int px = i & 63;
        const float s = red[0][px][o] + red[1][px][o] + red[2][px][o] + red[3][px][o]
                      + bias[o];
        offs[(((size_t)b * OffC + o) * Hn + row) * Wn + (half << 6) + px] = s;
    }
}

// ---------- Kernel 2: grouped deformable conv, 2 px/thread, no LDS ----------
// grid (Hn/4, Bn*NG), 256 threads. Weights via uniform global ptr -> s_load.
// Per tap: batched 128-load sample phase, then o-FMA phase. k unrolled x3.
__global__ __launch_bounds__(256, 4) void deform_kernel(
    const float* __restrict__ skip, const float* __restrict__ offs,
    const float* __restrict__ wt, float* __restrict__ out)
{
    const int tid = threadIdx.x;
    const int g   = blockIdx.y & 3;
    const int b   = blockIdx.y >> 2;
    const int col = tid & 127;
    const int r0  = blockIdx.x * 4 + (tid >> 7) * 2;   // rows r0, r0+1

    float acc0[Cg], acc1[Cg];
#pragma unroll
    for (int o = 0; o < Cg; o++) { acc0[o] = 0.f; acc1[o] = 0.f; }

    const float* sg   = skip + (size_t)(b * Cn + g * Cg) * HW;
    const float* wg   = wt + g * (KK * Cg * Cg);
    const float* offp = offs + (size_t)b * OffC * HW + r0 * Wn + col;

#pragma unroll 3
    for (int k = 0; k < KK; ++k) {
        const int ky = k / 3, kx = k % 3;
        // offset loads for both rows (4 independent loads)
        const float oy0 = offp[(2 * k) * HW];
        const float ox0 = offp[(2 * k + 1) * HW];
        const float oy1 = offp[(2 * k) * HW + Wn];
        const float ox1 = offp[(2 * k + 1) * HW + Wn];

        int ia0, ia1, ia2, ia3, ib0, ib1, ib2, ib3;
        float ma0, ma1, ma2, ma3, mb0, mb1, mb2, mb3;
        {   // pixel 0 (row r0)
            const float py = (float)(r0 - 1 + ky) + oy0;
            const float px = (float)(col - 1 + kx) + ox0;
            const float y0f = floorf(py), x0f = floorf(px);
            const float wy = py - y0f, wx = px - x0f;
            const int y0 = (int)y0f, x0 = (int)x0f, y1 = y0 + 1, x1 = x0 + 1;
            const bool vy0 = ((unsigned)y0 < (unsigned)Hn), vy1 = ((unsigned)y1 < (unsigned)Hn);
            const bool vx0 = ((unsigned)x0 < (unsigned)Wn), vx1 = ((unsigned)x1 < (unsigned)Wn);
            const int y0c = min(max(y0, 0), Hn - 1), y1c = min(max(y1, 0), Hn - 1);
            const int x0c = min(max(x0, 0), Wn - 1), x1c = min(max(x1, 0), Wn - 1);
            ma0 = (1.f - wy) * (1.f - wx) * ((vy0 && vx0) ? 1.f : 0.f);
            ma1 = (1.f - wy) * wx         * ((vy0 && vx1) ? 1.f : 0.f);
            ma2 = wy * (1.f - wx)         * ((vy1 && vx0) ? 1.f : 0.f);
            ma3 = wy * wx                 * ((vy1 && vx1) ? 1.f : 0.f);
            ia0 = y0c * Wn + x0c; ia1 = y0c * Wn + x1c;
            ia2 = y1c * Wn + x0c; ia3 = y1c * Wn + x1c;
        }
        {   // pixel 1 (row r0+1)
            const float py = (float)(r0 + ky) + oy1;
            const float px = (float)(col - 1 + kx) + ox1;
            const float y0f = floorf(py), x0f = floorf(px);
            const float wy = py - y0f, wx = px - x0f;
            const int y0 = (int)y0f, x0 = (int)x0f, y1 = y0 + 1, x1 = x0 + 1;
            const bool vy0 = ((unsigned)y0 < (unsigned)Hn), vy1 = ((unsigned)y1 < (unsigned)Hn);
            const bool vx0 = ((unsigned)x0 < (unsigned)Wn), vx1 = ((unsigned)x1 < (unsigned)Wn);
            const int y0c = min(max(y0, 0), Hn - 1), y1c = min(max(y1, 0), Hn - 1);
            const int x0c = min(max(x0, 0), Wn - 1), x1c = min(max(x1, 0), Wn - 1);
            mb0 = (1.f - wy) * (1.f - wx) * ((vy0 && vx0) ? 1.f : 0.f);
            mb1 = (1.f - wy) * wx         * ((vy0 && vx1) ? 1.f : 0.f);
            mb2 = wy * (1.f - wx)         * ((vy1 && vx0) ? 1.f : 0.f);
            mb3 = wy * wx                 * ((vy1 && vx1) ? 1.f : 0.f);
            ib0 = y0c * Wn + x0c; ib1 = y0c * Wn + x1c;
            ib2 = y1c * Wn + x0c; ib3 = y1c * Wn + x1c;
        }

        // sample phase: 128 independent gathers -> s0[16], s1[16]
        float s0[Cg], s1[Cg];
#pragma unroll
        for (int c = 0; c < Cg; ++c) {
            const float* sc = sg + c * HW;
            s0[c] = sc[ia0] * ma0 + sc[ia1] * ma1 + sc[ia2] * ma2 + sc[ia3] * ma3;
            s1[c] = sc[ib0] * mb0 + sc[ib1] * mb1 + sc[ib2] * mb2 + sc[ib3] * mb3;
        }
        // contraction phase: weights via s_load broadcast
#pragma unroll
        for (int c = 0; c < Cg; ++c) {
            const float* wr = wg + (k * Cg + c) * Cg;   // uniform address
#pragma unroll
            for (int o = 0; o < Cg; ++o) {
                const float wv = wr[o];
                acc0[o] += s0[c] * wv;
                acc1[o] += s1[c] * wv;
            }
        }
    }

    {
        float* ob0 = out + (((size_t)(b * Cn + g * Cg)) * Hn + r0) * Wn + col;
#pragma unroll
        for (int o = 0; o < Cg; o++) {
            ob0[o * HW]      = acc0[o];
            ob0[o * HW + Wn] = acc1[o];
        }
    }
}

extern "C" void kernel_launch(void* const* d_in, const int* in_sizes, int n_in,
                              void* d_out, int out_size, void* d_ws, size_t ws_size,
                              hipStream_t stream) {
    const float* x        = (const float*)d_in[0];
    const float* skip     = (const float*)d_in[1];
    const float* offset_w = (const float*)d_in[2];
    const float* offset_b = (const float*)d_in[3];
    const float* deform_w = (const float*)d_in[4];
    float* out  = (float*)d_out;

    float* offs = (float*)d_ws;               // 9.44 MB
    float* wt2  = offs + OFFS_ELEMS;          // 41.5 KB
    float* wt   = wt2 + WT2_ELEMS;            // 9.2 KB

    hipLaunchKernelGGL(transpose_w_kernel, dim3(8), dim3(256), 0, stream,
                       offset_w, deform_w, wt2, wt);
    hipLaunchKernelGGL(offset_conv_kernel, dim3(Bn * Hn * 2), dim3(256), 0, stream,
                       x, wt2, offset_b, offs);
    hipLaunchKernelGGL(deform_kernel, dim3(Hn / 4, Bn * NG), dim3(256), 0, stream,
                       skip, offs, wt, out);
}

// Round 5
// 260.256 us; speedup vs baseline: 7.0300x; 7.0300x over previous
//
#include <hip/hip_runtime.h>

#define Bn    8
#define Cn    64
#define Hn    128
#define Wn    128
#define KK    9
#define OffC  18
#define OffCp 20        // padded to float4 granularity
#define NG    4
#define Cg    16
#define HW    (Hn*Wn)
#define CSPLIT 4
#define CCH   (Cn/CSPLIT)   // 16 input channels per block

#define OFFS_ELEMS (Bn*OffC*HW)     // 2359296 floats
#define WT2_ELEMS  (Cn*KK*OffCp)    // 11520
#define WT_ELEMS   (NG*KK*Cg*Cg)    // 2304

// ---------- Kernel 0a: transpose weights into contraction-friendly layouts ----------
__global__ __launch_bounds__(256) void transpose_w_kernel(
    const float* __restrict__ offw, const float* __restrict__ dw,
    float* __restrict__ wt2, float* __restrict__ wt)
{
    const int tid = blockIdx.x * 256 + threadIdx.x;
    const int nth = gridDim.x * 256;
    for (int i = tid; i < WT2_ELEMS; i += nth) {
        const int o  = i % OffCp;
        const int k  = (i / OffCp) % KK;
        const int ci = i / (OffCp * KK);
        wt2[i] = (o < OffC) ? offw[(o * Cn + ci) * KK + k] : 0.f;
    }
    for (int i = tid; i < WT_ELEMS; i += nth) {
        const int o = i % Cg;
        const int c = (i / Cg) % Cg;
        const int k = (i / (Cg * Cg)) % KK;
        const int g = i / (Cg * Cg * KK);
        wt[i] = dw[((g * Cg + o) * Cg + c) * KK + k];
    }
}

// ---------- Kernel 0b: init offs with bias ----------
__global__ __launch_bounds__(256) void init_offs_kernel(
    const float* __restrict__ bias, float* __restrict__ offs)
{
    const int i4 = blockIdx.x * 256 + threadIdx.x;
    if (i4 * 4 >= OFFS_ELEMS) return;
    const int o = ((i4 * 4) / HW) % OffC;
    const float bv = bias[o];
    ((float4*)offs)[i4] = make_float4(bv, bv, bv, bv);
}

// ---------- Kernel 1: offset conv (3x3, 64->18, pad 1), ci-split x4, atomic finish ----
// (proven ~35-45 us in round 3 — unchanged)
__global__ __launch_bounds__(256, 4) void offset_conv_kernel(
    const float* __restrict__ x, const float* __restrict__ wt2,
    float* __restrict__ offs)
{
    __shared__ float wl[CCH * KK * OffCp];   // 11.5 KB
    const int tid = threadIdx.x;
    const int ci0 = blockIdx.z * CCH;
    {
        const float* src = wt2 + ci0 * (KK * OffCp);
        for (int i = tid; i < CCH * KK * OffCp; i += 256) wl[i] = src[i];
    }
    __syncthreads();

    const int b   = blockIdx.y;
    const int col = tid & 127;
    const int rp  = tid >> 7;
    const int r0  = blockIdx.x * 4 + rp * 2;

    float acc[2][OffC];
#pragma unroll
    for (int p = 0; p < 2; p++)
#pragma unroll
        for (int o = 0; o < OffC; o++) acc[p][o] = 0.f;

    const float* xb = x + ((size_t)b * Cn + ci0) * HW;
    for (int i = 0; i < CCH; ++i) {
        const float* xc = xb + i * HW;
        float rowv[4][3];
#pragma unroll
        for (int rr = 0; rr < 4; ++rr) {
            const int  y   = r0 - 1 + rr;
            const bool yok = ((unsigned)y < (unsigned)Hn);
#pragma unroll
            for (int kx = 0; kx < 3; ++kx) {
                const int xcol = col - 1 + kx;
                rowv[rr][kx] = (yok && (unsigned)xcol < (unsigned)Wn)
                               ? xc[y * Wn + xcol] : 0.f;
            }
        }
        const float* wci = wl + i * (KK * OffCp);
#pragma unroll
        for (int ky = 0; ky < 3; ++ky) {
#pragma unroll
            for (int kx = 0; kx < 3; ++kx) {
                const float4* wk4 = (const float4*)(wci + (ky * 3 + kx) * OffCp);
                const float4 w0 = wk4[0], w1 = wk4[1], w2 = wk4[2], w3 = wk4[3];
                const float2 w4 = *(const float2*)(wk4 + 4);
                const float w[OffC] = { w0.x,w0.y,w0.z,w0.w, w1.x,w1.y,w1.z,w1.w,
                                        w2.x,w2.y,w2.z,w2.w, w3.x,w3.y,w3.z,w3.w,
                                        w4.x,w4.y };
#pragma unroll
                for (int p = 0; p < 2; p++) {
                    const float v = rowv[p + ky][kx];
#pragma unroll
                    for (int o = 0; o < OffC; o++) acc[p][o] += v * w[o];
                }
            }
        }
    }

#pragma unroll
    for (int p = 0; p < 2; p++) {
        float* ob = offs + (((size_t)b * OffC) * Hn + (r0 + p)) * Wn + col;
#pragma unroll
        for (int o = 0; o < OffC; o++) atomicAdd(ob + o * HW, acc[p][o]);
    }
}

// ---------- Kernel 2: grouped deformable conv, 2 px/thread, staged gathers ----------
// LDS float4 weights (broadcast), explicit s0/s1 staging for MLP, k unrolled x2.
__global__ __launch_bounds__(256, 4) void deform_kernel(
    const float* __restrict__ skip, const float* __restrict__ offs,
    const float* __restrict__ wt, float* __restrict__ out)
{
    __shared__ float wl[KK * Cg * Cg];   // 9.2 KB
    const int tid = threadIdx.x;
    const int g = blockIdx.y & 3;
    const int b = blockIdx.y >> 2;
    for (int i = tid; i < KK * Cg * Cg; i += 256) wl[i] = wt[g * (KK * Cg * Cg) + i];
    __syncthreads();

    const int col = tid & 127;
    const int r0  = blockIdx.x * 4 + (tid >> 7) * 2;   // rows r0, r0+1

    float acc0[Cg], acc1[Cg];
#pragma unroll
    for (int o = 0; o < Cg; o++) { acc0[o] = 0.f; acc1[o] = 0.f; }

    const float* sg   = skip + (size_t)(b * Cn + g * Cg) * HW;
    const float* offp = offs + (size_t)b * OffC * HW + r0 * Wn + col;

#pragma unroll 2
    for (int k = 0; k < KK; ++k) {
        const int ky = k / 3, kx = k % 3;
        const float oy0 = offp[(2 * k) * HW];
        const float ox0 = offp[(2 * k + 1) * HW];
        const float oy1 = offp[(2 * k) * HW + Wn];
        const float ox1 = offp[(2 * k + 1) * HW + Wn];

        int ia0, ia1, ia2, ia3, ib0, ib1, ib2, ib3;
        float ma0, ma1, ma2, ma3, mb0, mb1, mb2, mb3;
        {   // pixel 0 (row r0)
            const float py = (float)(r0 - 1 + ky) + oy0;
            const float px = (float)(col - 1 + kx) + ox0;
            const float y0f = floorf(py), x0f = floorf(px);
            const float wy = py - y0f, wx = px - x0f;
            const int y0 = (int)y0f, x0 = (int)x0f, y1 = y0 + 1, x1 = x0 + 1;
            const bool vy0 = ((unsigned)y0 < (unsigned)Hn), vy1 = ((unsigned)y1 < (unsigned)Hn);
            const bool vx0 = ((unsigned)x0 < (unsigned)Wn), vx1 = ((unsigned)x1 < (unsigned)Wn);
            const int y0c = min(max(y0, 0), Hn - 1), y1c = min(max(y1, 0), Hn - 1);
            const int x0c = min(max(x0, 0), Wn - 1), x1c = min(max(x1, 0), Wn - 1);
            ma0 = (1.f - wy) * (1.f - wx) * ((vy0 && vx0) ? 1.f : 0.f);
            ma1 = (1.f - wy) * wx         * ((vy0 && vx1) ? 1.f : 0.f);
            ma2 = wy * (1.f - wx)         * ((vy1 && vx0) ? 1.f : 0.f);
            ma3 = wy * wx                 * ((vy1 && vx1) ? 1.f : 0.f);
            ia0 = y0c * Wn + x0c; ia1 = y0c * Wn + x1c;
            ia2 = y1c * Wn + x0c; ia3 = y1c * Wn + x1c;
        }
        {   // pixel 1 (row r0+1)
            const float py = (float)(r0 + ky) + oy1;
            const float px = (float)(col - 1 + kx) + ox1;
            const float y0f = floorf(py), x0f = floorf(px);
            const float wy = py - y0f, wx = px - x0f;
            const int y0 = (int)y0f, x0 = (int)x0f, y1 = y0 + 1, x1 = x0 + 1;
            const bool vy0 = ((unsigned)y0 < (unsigned)Hn), vy1 = ((unsigned)y1 < (unsigned)Hn);
            const bool vx0 = ((unsigned)x0 < (unsigned)Wn), vx1 = ((unsigned)x1 < (unsigned)Wn);
            const int y0c = min(max(y0, 0), Hn - 1), y1c = min(max(y1, 0), Hn - 1);
            const int x0c = min(max(x0, 0), Wn - 1), x1c = min(max(x1, 0), Wn - 1);
            mb0 = (1.f - wy) * (1.f - wx) * ((vy0 && vx0) ? 1.f : 0.f);
            mb1 = (1.f - wy) * wx         * ((vy0 && vx1) ? 1.f : 0.f);
            mb2 = wy * (1.f - wx)         * ((vy1 && vx0) ? 1.f : 0.f);
            mb3 = wy * wx                 * ((vy1 && vx1) ? 1.f : 0.f);
            ib0 = y0c * Wn + x0c; ib1 = y0c * Wn + x1c;
            ib2 = y1c * Wn + x0c; ib3 = y1c * Wn + x1c;
        }

        // ---- sample phase: 128 independent gathers staged into registers ----
        float s0[Cg], s1[Cg];
#pragma unroll
        for (int c = 0; c < Cg; ++c) {
            const float* sc = sg + c * HW;
            const float a0 = sc[ia0], a1 = sc[ia1], a2 = sc[ia2], a3 = sc[ia3];
            const float b0 = sc[ib0], b1 = sc[ib1], b2 = sc[ib2], b3 = sc[ib3];
            s0[c] = a0 * ma0 + a1 * ma1 + a2 * ma2 + a3 * ma3;
            s1[c] = b0 * mb0 + b1 * mb1 + b2 * mb2 + b3 * mb3;
        }

        // ---- contraction phase: LDS float4 broadcast weights ----
#pragma unroll
        for (int c = 0; c < Cg; ++c) {
            const float4* wc4 = (const float4*)(wl + (k * Cg + c) * Cg);
            const float4 w0 = wc4[0], w1 = wc4[1], w2 = wc4[2], w3 = wc4[3];
            const float w[Cg] = { w0.x,w0.y,w0.z,w0.w, w1.x,w1.y,w1.z,w1.w,
                                  w2.x,w2.y,w2.z,w2.w, w3.x,w3.y,w3.z,w3.w };
            const float v0 = s0[c], v1 = s1[c];
#pragma unroll
            for (int o = 0; o < Cg; ++o) {
                acc0[o] += v0 * w[o];
                acc1[o] += v1 * w[o];
            }
        }
    }

    {
        float* ob0 = out + (((size_t)(b * Cn + g * Cg)) * Hn + r0) * Wn + col;
#pragma unroll
        for (int o = 0; o < Cg; o++) {
            ob0[o * HW]      = acc0[o];
            ob0[o * HW + Wn] = acc1[o];
        }
    }
}

extern "C" void kernel_launch(void* const* d_in, const int* in_sizes, int n_in,
                              void* d_out, int out_size, void* d_ws, size_t ws_size,
                              hipStream_t stream) {
    const float* x        = (const float*)d_in[0];
    const float* skip     = (const float*)d_in[1];
    const float* offset_w = (const float*)d_in[2];
    const float* offset_b = (const float*)d_in[3];
    const float* deform_w = (const float*)d_in[4];
    float* out  = (float*)d_out;

    float* offs = (float*)d_ws;               // 9.44 MB
    float* wt2  = offs + OFFS_ELEMS;          // 46 KB
    float* wt   = wt2 + WT2_ELEMS;            // 9.2 KB

    hipLaunchKernelGGL(transpose_w_kernel, dim3(8), dim3(256), 0, stream,
                       offset_w, deform_w, wt2, wt);
    hipLaunchKernelGGL(init_offs_kernel, dim3((OFFS_ELEMS / 4 + 255) / 256), dim3(256),
                       0, stream, offset_b, offs);
    hipLaunchKernelGGL(offset_conv_kernel, dim3(Hn / 4, Bn, CSPLIT), dim3(256),
                       0, stream, x, wt2, offs);
    hipLaunchKernelGGL(deform_kernel, dim3(Hn / 4, Bn * NG), dim3(256),
                       0, stream, skip, offs, wt, out);
}

// Round 6
// 132.131 us; speedup vs baseline: 13.8469x; 1.9697x over previous
//
#include <hip/hip_runtime.h>

#define Bn    8
#define Cn    64
#define Hn    128
#define Wn    128
#define KK    9
#define OffC  18
#define OffCp 20
#define NG    4
#define Cg    16
#define HW    (Hn*Wn)
#define CSPLIT 4
#define CCH   (Cn/CSPLIT)

#define OFFS_ELEMS (Bn*OffC*HW)
#define WT2_ELEMS  (Cn*KK*OffCp)
#define WT_ELEMS   (NG*KK*Cg*Cg)

// deform tile geometry
#define ROWS  8                  // output rows per block
#define TR    15                 // staged rows: ROWS + 3 halo above + 4 below
#define NW    8                  // bf16 channel-pair words (16 ch)

// ---------- Kernel 0a: transpose weights ----------
__global__ __launch_bounds__(256) void transpose_w_kernel(
    const float* __restrict__ offw, const float* __restrict__ dw,
    float* __restrict__ wt2, float* __restrict__ wt)
{
    const int tid = blockIdx.x * 256 + threadIdx.x;
    const int nth = gridDim.x * 256;
    for (int i = tid; i < WT2_ELEMS; i += nth) {
        const int o  = i % OffCp;
        const int k  = (i / OffCp) % KK;
        const int ci = i / (OffCp * KK);
        wt2[i] = (o < OffC) ? offw[(o * Cn + ci) * KK + k] : 0.f;
    }
    for (int i = tid; i < WT_ELEMS; i += nth) {
        const int o = i % Cg;
        const int c = (i / Cg) % Cg;
        const int k = (i / (Cg * Cg)) % KK;
        const int g = i / (Cg * Cg * KK);
        wt[i] = dw[((g * Cg + o) * Cg + c) * KK + k];
    }
}

// ---------- Kernel 0b: init offs with bias ----------
__global__ __launch_bounds__(256) void init_offs_kernel(
    const float* __restrict__ bias, float* __restrict__ offs)
{
    const int i4 = blockIdx.x * 256 + threadIdx.x;
    if (i4 * 4 >= OFFS_ELEMS) return;
    const int o = ((i4 * 4) / HW) % OffC;
    const float bv = bias[o];
    ((float4*)offs)[i4] = make_float4(bv, bv, bv, bv);
}

// ---------- Kernel 1: offset conv — unchanged from round 3 (proven ~46 us stack) ----
__global__ __launch_bounds__(256, 4) void offset_conv_kernel(
    const float* __restrict__ x, const float* __restrict__ wt2,
    float* __restrict__ offs)
{
    __shared__ float wl[CCH * KK * OffCp];
    const int tid = threadIdx.x;
    const int ci0 = blockIdx.z * CCH;
    {
        const float* src = wt2 + ci0 * (KK * OffCp);
        for (int i = tid; i < CCH * KK * OffCp; i += 256) wl[i] = src[i];
    }
    __syncthreads();

    const int b   = blockIdx.y;
    const int col = tid & 127;
    const int rp  = tid >> 7;
    const int r0  = blockIdx.x * 4 + rp * 2;

    float acc[2][OffC];
#pragma unroll
    for (int p = 0; p < 2; p++)
#pragma unroll
        for (int o = 0; o < OffC; o++) acc[p][o] = 0.f;

    const float* xb = x + ((size_t)b * Cn + ci0) * HW;
    for (int i = 0; i < CCH; ++i) {
        const float* xc = xb + i * HW;
        float rowv[4][3];
#pragma unroll
        for (int rr = 0; rr < 4; ++rr) {
            const int  y   = r0 - 1 + rr;
            const bool yok = ((unsigned)y < (unsigned)Hn);
#pragma unroll
            for (int kx = 0; kx < 3; ++kx) {
                const int xcol = col - 1 + kx;
                rowv[rr][kx] = (yok && (unsigned)xcol < (unsigned)Wn)
                               ? xc[y * Wn + xcol] : 0.f;
            }
        }
        const float* wci = wl + i * (KK * OffCp);
#pragma unroll
        for (int ky = 0; ky < 3; ++ky) {
#pragma unroll
            for (int kx = 0; kx < 3; ++kx) {
                const float4* wk4 = (const float4*)(wci + (ky * 3 + kx) * OffCp);
                const float4 w0 = wk4[0], w1 = wk4[1], w2 = wk4[2], w3 = wk4[3];
                const float2 w4 = *(const float2*)(wk4 + 4);
                const float w[OffC] = { w0.x,w0.y,w0.z,w0.w, w1.x,w1.y,w1.z,w1.w,
                                        w2.x,w2.y,w2.z,w2.w, w3.x,w3.y,w3.z,w3.w,
                                        w4.x,w4.y };
#pragma unroll
                for (int p = 0; p < 2; p++) {
                    const float v = rowv[p + ky][kx];
#pragma unroll
                    for (int o = 0; o < OffC; o++) acc[p][o] += v * w[o];
                }
            }
        }
    }

#pragma unroll
    for (int p = 0; p < 2; p++) {
        float* ob = offs + (((size_t)b * OffC) * Hn + (r0 + p)) * Wn + col;
#pragma unroll
        for (int o = 0; o < OffC; o++) atomicAdd(ob + o * HW, acc[p][o]);
    }
}

// ---------- Kernel 2: deform conv — LDS bf16-pair tile gather ----------
// grid (Hn/ROWS, Bn*NG), 512 threads. Thread: 1 col x 2 rows, 16 out channels.
__global__ __launch_bounds__(512, 4) void deform_kernel(
    const float* __restrict__ skip, const float* __restrict__ offs,
    const float* __restrict__ wt, float* __restrict__ out)
{
    __shared__ unsigned int tile[NW * TR * Wn];   // 61440 B
    __shared__ float wl[KK * Cg * Cg];            // 9216 B

    const int tid = threadIdx.x;
    const int g = blockIdx.y & 3;
    const int b = blockIdx.y >> 2;
    const int r0  = blockIdx.x * ROWS;
    const int ylo = max(0, r0 - 3);
    const int yhi = min(Hn - 1, r0 + ROWS + 3);
    const int nr1 = yhi - ylo;                    // nrows-1

    const float* sg = skip + (size_t)(b * Cn + g * Cg) * HW;

    for (int i = tid; i < KK * Cg * Cg; i += 512) wl[i] = wt[g * (KK * Cg * Cg) + i];

    // stage skip window as bf16 channel-pairs: tile[w][ty][x], ch(2w) low, ch(2w+1) high
    for (int i = tid; i < NW * TR * Wn; i += 512) {
        const int w  = i / (TR * Wn);
        const int re = i % (TR * Wn);
        const int ty = re >> 7;
        const int xx = re & 127;
        const int y  = ylo + ty;
        if (y <= yhi) {
            const float f0 = sg[(2 * w)     * HW + y * Wn + xx];
            const float f1 = sg[(2 * w + 1) * HW + y * Wn + xx];
            unsigned int b0 = __float_as_uint(f0);
            b0 = (b0 + 0x7FFFu + ((b0 >> 16) & 1u)) >> 16;
            unsigned int b1 = __float_as_uint(f1);
            b1 = (b1 + 0x7FFFu + ((b1 >> 16) & 1u)) & 0xFFFF0000u;
            tile[i] = b1 | b0;
        }
    }
    __syncthreads();

    const int col = tid & 127;
    const int rp  = tid >> 7;            // 0..3
    const int ro0 = r0 + rp * 2;         // this thread's rows: ro0, ro0+1

    float acc0[Cg], acc1[Cg];
#pragma unroll
    for (int o = 0; o < Cg; o++) { acc0[o] = 0.f; acc1[o] = 0.f; }

    const float* offp = offs + (size_t)b * OffC * HW + ro0 * Wn + col;

#pragma unroll 1
    for (int k = 0; k < KK; ++k) {
        const int ky = k / 3, kx = k % 3;
        const float oy0 = offp[(2 * k) * HW];
        const float ox0 = offp[(2 * k + 1) * HW];
        const float oy1 = offp[(2 * k) * HW + Wn];
        const float ox1 = offp[(2 * k + 1) * HW + Wn];

        int ia0, ia1, ia2, ia3, ib0, ib1, ib2, ib3;     // global fallback indices
        int ta0, ta1, ta2, ta3, tb0, tb1, tb2, tb3;     // LDS tile word indices
        float ma0, ma1, ma2, ma3, mb0, mb1, mb2, mb3;
        bool cond0, cond1;
        {   // pixel 0 (row ro0)
            const float py = (float)(ro0 - 1 + ky) + oy0;
            const float px = (float)(col - 1 + kx) + ox0;
            const float y0f = floorf(py), x0f = floorf(px);
            const float wy = py - y0f, wx = px - x0f;
            const int y0 = (int)y0f, x0 = (int)x0f, y1 = y0 + 1, x1 = x0 + 1;
            const bool vy0 = ((unsigned)y0 < (unsigned)Hn), vy1 = ((unsigned)y1 < (unsigned)Hn);
            const bool vx0 = ((unsigned)x0 < (unsigned)Wn), vx1 = ((unsigned)x1 < (unsigned)Wn);
            const int y0c = min(max(y0, 0), Hn - 1), y1c = min(max(y1, 0), Hn - 1);
            const int x0c = min(max(x0, 0), Wn - 1), x1c = min(max(x1, 0), Wn - 1);
            ma0 = (1.f - wy) * (1.f - wx) * ((vy0 && vx0) ? 1.f : 0.f);
            ma1 = (1.f - wy) * wx         * ((vy0 && vx1) ? 1.f : 0.f);
            ma2 = wy * (1.f - wx)         * ((vy1 && vx0) ? 1.f : 0.f);
            ma3 = wy * wx                 * ((vy1 && vx1) ? 1.f : 0.f);
            ia0 = y0c * Wn + x0c; ia1 = y0c * Wn + x1c;
            ia2 = y1c * Wn + x0c; ia3 = y1c * Wn + x1c;
            cond0 = (y0c >= ylo) && (y1c <= yhi);
            const int t0 = min(max(y0c - ylo, 0), nr1), t1 = min(max(y1c - ylo, 0), nr1);
            ta0 = t0 * Wn + x0c; ta1 = t0 * Wn + x1c;
            ta2 = t1 * Wn + x0c; ta3 = t1 * Wn + x1c;
        }
        {   // pixel 1 (row ro0+1)
            const float py = (float)(ro0 + ky) + oy1;
            const float px = (float)(col - 1 + kx) + ox1;
            const float y0f = floorf(py), x0f = floorf(px);
            const float wy = py - y0f, wx = px - x0f;
            const int y0 = (int)y0f, x0 = (int)x0f, y1 = y0 + 1, x1 = x0 + 1;
            const bool vy0 = ((unsigned)y0 < (unsigned)Hn), vy1 = ((unsigned)y1 < (unsigned)Hn);
            const bool vx0 = ((unsigned)x0 < (unsigned)Wn), vx1 = ((unsigned)x1 < (unsigned)Wn);
            const int y0c = min(max(y0, 0), Hn - 1), y1c = min(max(y1, 0), Hn - 1);
            const int x0c = min(max(x0, 0), Wn - 1), x1c = min(max(x1, 0), Wn - 1);
            mb0 = (1.f - wy) * (1.f - wx) * ((vy0 && vx0) ? 1.f : 0.f);
            mb1 = (1.f - wy) * wx         * ((vy0 && vx1) ? 1.f : 0.f);
            mb2 = wy * (1.f - wx)         * ((vy1 && vx0) ? 1.f : 0.f);
            mb3 = wy * wx                 * ((vy1 && vx1) ? 1.f : 0.f);
            ib0 = y0c * Wn + x0c; ib1 = y0c * Wn + x1c;
            ib2 = y1c * Wn + x0c; ib3 = y1c * Wn + x1c;
            cond1 = (y0c >= ylo) && (y1c <= yhi);
            const int t0 = min(max(y0c - ylo, 0), nr1), t1 = min(max(y1c - ylo, 0), nr1);
            tb0 = t0 * Wn + x0c; tb1 = t0 * Wn + x1c;
            tb2 = t1 * Wn + x0c; tb3 = t1 * Wn + x1c;
        }

        // ---- sample from LDS tile (bf16 pairs, 2 channels per read) ----
        float s0[Cg], s1[Cg];
#pragma unroll
        for (int w = 0; w < NW; ++w) {
            const int base = w * (TR * Wn);
            const unsigned int u00 = tile[base + ta0], u01 = tile[base + ta1];
            const unsigned int u10 = tile[base + ta2], u11 = tile[base + ta3];
            s0[2*w]   = __uint_as_float(u00 << 16) * ma0 + __uint_as_float(u01 << 16) * ma1
                      + __uint_as_float(u10 << 16) * ma2 + __uint_as_float(u11 << 16) * ma3;
            s0[2*w+1] = __uint_as_float(u00 & 0xFFFF0000u) * ma0 + __uint_as_float(u01 & 0xFFFF0000u) * ma1
                      + __uint_as_float(u10 & 0xFFFF0000u) * ma2 + __uint_as_float(u11 & 0xFFFF0000u) * ma3;
            const unsigned int v00 = tile[base + tb0], v01 = tile[base + tb1];
            const unsigned int v10 = tile[base + tb2], v11 = tile[base + tb3];
            s1[2*w]   = __uint_as_float(v00 << 16) * mb0 + __uint_as_float(v01 << 16) * mb1
                      + __uint_as_float(v10 << 16) * mb2 + __uint_as_float(v11 << 16) * mb3;
            s1[2*w+1] = __uint_as_float(v00 & 0xFFFF0000u) * mb0 + __uint_as_float(v01 & 0xFFFF0000u) * mb1
                      + __uint_as_float(v10 & 0xFFFF0000u) * mb2 + __uint_as_float(v11 & 0xFFFF0000u) * mb3;
        }
        // ---- rare fallback: sample fell outside staged rows -> global fp32 ----
        if (!cond0) {
#pragma unroll
            for (int c = 0; c < Cg; ++c) {
                const float* sc = sg + c * HW;
                s0[c] = sc[ia0] * ma0 + sc[ia1] * ma1 + sc[ia2] * ma2 + sc[ia3] * ma3;
            }
        }
        if (!cond1) {
#pragma unroll
            for (int c = 0; c < Cg; ++c) {
                const float* sc = sg + c * HW;
                s1[c] = sc[ib0] * mb0 + sc[ib1] * mb1 + sc[ib2] * mb2 + sc[ib3] * mb3;
            }
        }

        // ---- contraction: LDS float4 broadcast weights ----
#pragma unroll
        for (int c = 0; c < Cg; ++c) {
            const float4* wc4 = (const float4*)(wl + (k * Cg + c) * Cg);
            const float4 w0 = wc4[0], w1 = wc4[1], w2 = wc4[2], w3 = wc4[3];
            const float w[Cg] = { w0.x,w0.y,w0.z,w0.w, w1.x,w1.y,w1.z,w1.w,
                                  w2.x,w2.y,w2.z,w2.w, w3.x,w3.y,w3.z,w3.w };
            const float v0 = s0[c], v1 = s1[c];
#pragma unroll
            for (int o = 0; o < Cg; ++o) {
                acc0[o] += v0 * w[o];
                acc1[o] += v1 * w[o];
            }
        }
    }

    {
        float* ob0 = out + (((size_t)(b * Cn + g * Cg)) * Hn + ro0) * Wn + col;
#pragma unroll
        for (int o = 0; o < Cg; o++) {
            ob0[o * HW]      = acc0[o];
            ob0[o * HW + Wn] = acc1[o];
        }
    }
}

extern "C" void kernel_launch(void* const* d_in, const int* in_sizes, int n_in,
                              void* d_out, int out_size, void* d_ws, size_t ws_size,
                              hipStream_t stream) {
    const float* x        = (const float*)d_in[0];
    const float* skip     = (const float*)d_in[1];
    const float* offset_w = (const float*)d_in[2];
    const float* offset_b = (const float*)d_in[3];
    const float* deform_w = (const float*)d_in[4];
    float* out  = (float*)d_out;

    float* offs = (float*)d_ws;
    float* wt2  = offs + OFFS_ELEMS;
    float* wt   = wt2 + WT2_ELEMS;

    hipLaunchKernelGGL(transpose_w_kernel, dim3(8), dim3(256), 0, stream,
                       offset_w, deform_w, wt2, wt);
    hipLaunchKernelGGL(init_offs_kernel, dim3((OFFS_ELEMS / 4 + 255) / 256), dim3(256),
                       0, stream, offset_b, offs);
    hipLaunchKernelGGL(offset_conv_kernel, dim3(Hn / 4, Bn, CSPLIT), dim3(256),
                       0, stream, x, wt2, offs);
    hipLaunchKernelGGL(deform_kernel, dim3(Hn / ROWS, Bn * NG), dim3(512),
                       0, stream, skip, offs, wt, out);
}

// Round 7
// 118.391 us; speedup vs baseline: 15.4539x; 1.1161x over previous
//
#include <hip/hip_runtime.h>

#define Bn    8
#define Cn    64
#define Hn    128
#define Wn    128
#define KK    9
#define OffC  18
#define OffCp 20
#define NG    4
#define Cg    16
#define HW    (Hn*Wn)
#define CSPLIT 4
#define CCH   (Cn/CSPLIT)

#define OFFS_ELEMS (Bn*OffC*HW)
#define WT2_ELEMS  (Cn*KK*OffCp)
#define WA_ELEMS   (NG*KK*64*8)     // ushort (bf16) MFMA A-fragments

// deform tile geometry
#define ROWS  8
#define TR    15
#define NW    8
#define TSTR  132                   // padded col stride (breaks bank aliasing)

typedef __attribute__((ext_vector_type(8)))  short short8v;
typedef __attribute__((ext_vector_type(16))) float f32x16;

__device__ __forceinline__ unsigned int rne16(float f) {
    unsigned int u = __float_as_uint(f);
    return (u + 0x7FFFu + ((u >> 16) & 1u)) >> 16;   // bf16 round-to-nearest-even
}

// ---------- Kernel 0a: weight prep ----------
// wt2[ci][k][o] padded fp32 (offset conv, proven layout)
// wA[g][t][lane][8] bf16 A-fragments for mfma_32x32x16_bf16:
//   lane l -> row o = l&31 (o>=16 zero), k = c = 8*(l>>5) + elem
__global__ __launch_bounds__(256) void transpose_w_kernel(
    const float* __restrict__ offw, const float* __restrict__ dw,
    float* __restrict__ wt2, unsigned short* __restrict__ wA)
{
    const int tid = blockIdx.x * 256 + threadIdx.x;
    const int nth = gridDim.x * 256;
    for (int i = tid; i < WT2_ELEMS; i += nth) {
        const int o  = i % OffCp;
        const int k  = (i / OffCp) % KK;
        const int ci = i / (OffCp * KK);
        wt2[i] = (o < OffC) ? offw[(o * Cn + ci) * KK + k] : 0.f;
    }
    for (int i = tid; i < WA_ELEMS; i += nth) {
        const int e    = i % 8;
        const int lane = (i / 8) % 64;
        const int t    = (i / 512) % KK;
        const int g    = i / (512 * KK);
        const int o    = lane & 31;
        const int c    = 8 * (lane >> 5) + e;
        const float v  = (o < Cg) ? dw[((g * Cg + o) * Cg + c) * KK + t] : 0.f;
        wA[i] = (unsigned short)rne16(v);
    }
}

// ---------- Kernel 0b: init offs with bias ----------
__global__ __launch_bounds__(256) void init_offs_kernel(
    const float* __restrict__ bias, float* __restrict__ offs)
{
    const int i4 = blockIdx.x * 256 + threadIdx.x;
    if (i4 * 4 >= OFFS_ELEMS) return;
    const int o = ((i4 * 4) / HW) % OffC;
    const float bv = bias[o];
    ((float4*)offs)[i4] = make_float4(bv, bv, bv, bv);
}

// ---------- Kernel 1: offset conv (proven round-3 version, unchanged) ----------
__global__ __launch_bounds__(256, 4) void offset_conv_kernel(
    const float* __restrict__ x, const float* __restrict__ wt2,
    float* __restrict__ offs)
{
    __shared__ float wl[CCH * KK * OffCp];
    const int tid = threadIdx.x;
    const int ci0 = blockIdx.z * CCH;
    {
        const float* src = wt2 + ci0 * (KK * OffCp);
        for (int i = tid; i < CCH * KK * OffCp; i += 256) wl[i] = src[i];
    }
    __syncthreads();

    const int b   = blockIdx.y;
    const int col = tid & 127;
    const int rp  = tid >> 7;
    const int r0  = blockIdx.x * 4 + rp * 2;

    float acc[2][OffC];
#pragma unroll
    for (int p = 0; p < 2; p++)
#pragma unroll
        for (int o = 0; o < OffC; o++) acc[p][o] = 0.f;

    const float* xb = x + ((size_t)b * Cn + ci0) * HW;
    for (int i = 0; i < CCH; ++i) {
        const float* xc = xb + i * HW;
        float rowv[4][3];
#pragma unroll
        for (int rr = 0; rr < 4; ++rr) {
            const int  y   = r0 - 1 + rr;
            const bool yok = ((unsigned)y < (unsigned)Hn);
#pragma unroll
            for (int kx = 0; kx < 3; ++kx) {
                const int xcol = col - 1 + kx;
                rowv[rr][kx] = (yok && (unsigned)xcol < (unsigned)Wn)
                               ? xc[y * Wn + xcol] : 0.f;
            }
        }
        const float* wci = wl + i * (KK * OffCp);
#pragma unroll
        for (int ky = 0; ky < 3; ++ky) {
#pragma unroll
            for (int kx = 0; kx < 3; ++kx) {
                const float4* wk4 = (const float4*)(wci + (ky * 3 + kx) * OffCp);
                const float4 w0 = wk4[0], w1 = wk4[1], w2 = wk4[2], w3 = wk4[3];
                const float2 w4 = *(const float2*)(wk4 + 4);
                const float w[OffC] = { w0.x,w0.y,w0.z,w0.w, w1.x,w1.y,w1.z,w1.w,
                                        w2.x,w2.y,w2.z,w2.w, w3.x,w3.y,w3.z,w3.w,
                                        w4.x,w4.y };
#pragma unroll
                for (int p = 0; p < 2; p++) {
                    const float v = rowv[p + ky][kx];
#pragma unroll
                    for (int o = 0; o < OffC; o++) acc[p][o] += v * w[o];
                }
            }
        }
    }

#pragma unroll
    for (int p = 0; p < 2; p++) {
        float* ob = offs + (((size_t)b * OffC) * Hn + (r0 + p)) * Wn + col;
#pragma unroll
        for (int o = 0; o < OffC; o++) atomicAdd(ob + o * HW, acc[p][o]);
    }
}

// ---------- Kernel 2: deform conv — LDS bf16 tile gather + MFMA contraction ----------
// grid (Hn/ROWS, Bn*NG), 512 thr (8 waves). Wave w owns row r0+w; 4 chunks of 32 cols.
// lane l: pixel p = l&31 of the chunk, channel-half h = l>>5 (8 channels).
// Per (chunk, tap): lane samples 8 ch -> bf16x8 B-frag; A-frag = prepped weights;
// one mfma_f32_32x32x16_bf16 accumulates out[o][px] (o = D-rows 0..15, px = D-cols).
__global__ __launch_bounds__(512, 4) void deform_kernel(
    const float* __restrict__ skip, const float* __restrict__ offs,
    const unsigned short* __restrict__ wA, float* __restrict__ out)
{
    __shared__ unsigned int tile[NW * TR * TSTR];   // 63360 B

    const int tid = threadIdx.x;
    const int g = blockIdx.y & 3;
    const int b = blockIdx.y >> 2;
    const int r0  = blockIdx.x * ROWS;
    const int ylo = max(0, r0 - 3);
    const int yhi = min(Hn - 1, r0 + ROWS + 3);

    const float* sg = skip + (size_t)(b * Cn + g * Cg) * HW;

    // stage skip window as bf16 channel-pairs: tile[(w*TR+ty)*TSTR + x]
    for (int i = tid; i < NW * TR * Wn; i += 512) {
        const int w  = i / (TR * Wn);
        const int re = i % (TR * Wn);
        const int ty = re >> 7;
        const int xx = re & 127;
        const int y  = ylo + ty;
        if (y <= yhi) {
            const float f0 = sg[(2 * w)     * HW + y * Wn + xx];
            const float f1 = sg[(2 * w + 1) * HW + y * Wn + xx];
            const unsigned int b0 = rne16(f0);
            unsigned int b1 = __float_as_uint(f1);
            b1 = (b1 + 0x7FFFu + ((b1 >> 16) & 1u)) & 0xFFFF0000u;
            tile[(w * TR + ty) * TSTR + xx] = b1 | b0;
        }
    }
    __syncthreads();

    const int wv   = tid >> 6;          // wave 0..7 -> row
    const int lane = tid & 63;
    const int p    = lane & 31;         // pixel within chunk
    const int h    = lane >> 5;         // channel-half
    const int r    = r0 + wv;

    const unsigned short* wAg = wA + (size_t)g * (KK * 512) + lane * 8;
    const float* offb = offs + (size_t)b * OffC * HW + r * Wn;

    for (int j = 0; j < 4; ++j) {
        const int col = j * 32 + p;
        f32x16 acc;
#pragma unroll
        for (int i = 0; i < 16; ++i) acc[i] = 0.f;

        const float* offp = offb + col;

#pragma unroll 2
        for (int t = 0; t < KK; ++t) {
            const int ky = t / 3, kx = t % 3;
            const float offy = offp[(2 * t) * HW];
            const float offx = offp[(2 * t + 1) * HW];
            const float pyf = (float)(r - 1 + ky) + offy;
            const float pxf = (float)(col - 1 + kx) + offx;
            const float y0f = floorf(pyf), x0f = floorf(pxf);
            const float wy = pyf - y0f, wx = pxf - x0f;
            const int y0 = (int)y0f, x0 = (int)x0f, y1 = y0 + 1, x1 = x0 + 1;
            const bool vy0 = ((unsigned)y0 < (unsigned)Hn), vy1 = ((unsigned)y1 < (unsigned)Hn);
            const bool vx0 = ((unsigned)x0 < (unsigned)Wn), vx1 = ((unsigned)x1 < (unsigned)Wn);
            const int y0c = min(max(y0, 0), Hn - 1), y1c = min(max(y1, 0), Hn - 1);
            const int x0c = min(max(x0, 0), Wn - 1), x1c = min(max(x1, 0), Wn - 1);
            const float m0 = (1.f - wy) * (1.f - wx) * ((vy0 && vx0) ? 1.f : 0.f);
            const float m1 = (1.f - wy) * wx         * ((vy0 && vx1) ? 1.f : 0.f);
            const float m2 = wy * (1.f - wx)         * ((vy1 && vx0) ? 1.f : 0.f);
            const float m3 = wy * wx                 * ((vy1 && vx1) ? 1.f : 0.f);
            const bool cond = (y0c >= ylo) && (y1c <= yhi);

            float s[8];
            if (cond) {
                const int tr0 = y0c - ylo, tr1 = y1c - ylo;
#pragma unroll
                for (int wi = 0; wi < 4; ++wi) {
                    const unsigned int* tw = tile + ((4 * h + wi) * TR) * TSTR;
                    const unsigned int u00 = tw[tr0 * TSTR + x0c];
                    const unsigned int u01 = tw[tr0 * TSTR + x1c];
                    const unsigned int u10 = tw[tr1 * TSTR + x0c];
                    const unsigned int u11 = tw[tr1 * TSTR + x1c];
                    s[2 * wi]     = __uint_as_float(u00 << 16) * m0 + __uint_as_float(u01 << 16) * m1
                                  + __uint_as_float(u10 << 16) * m2 + __uint_as_float(u11 << 16) * m3;
                    s[2 * wi + 1] = __uint_as_float(u00 & 0xFFFF0000u) * m0 + __uint_as_float(u01 & 0xFFFF0000u) * m1
                                  + __uint_as_float(u10 & 0xFFFF0000u) * m2 + __uint_as_float(u11 & 0xFFFF0000u) * m3;
                }
            } else {
                const int ia0 = y0c * Wn + x0c, ia1 = y0c * Wn + x1c;
                const int ia2 = y1c * Wn + x0c, ia3 = y1c * Wn + x1c;
#pragma unroll
                for (int i = 0; i < 8; ++i) {
                    const float* sc = sg + (8 * h + i) * HW;
                    s[i] = sc[ia0] * m0 + sc[ia1] * m1 + sc[ia2] * m2 + sc[ia3] * m3;
                }
            }

            short8v bfrag;
#pragma unroll
            for (int i = 0; i < 8; ++i) bfrag[i] = (short)rne16(s[i]);
            const short8v afrag = *(const short8v*)(wAg + t * 512);

            acc = __builtin_amdgcn_mfma_f32_32x32x16_bf16(afrag, bfrag, acc, 0, 0, 0);
        }

        // store: D col = px (lane&31), D row = o = (reg&3) + 8*(reg>>2) + 4*h (regs 0..7 valid)
        float* ob = out + (size_t)(b * Cn + g * Cg) * HW + r * Wn + col;
#pragma unroll
        for (int reg = 0; reg < 8; ++reg) {
            const int o = (reg & 3) + 8 * (reg >> 2) + 4 * h;
            ob[o * HW] = acc[reg];
        }
    }
}

extern "C" void kernel_launch(void* const* d_in, const int* in_sizes, int n_in,
                              void* d_out, int out_size, void* d_ws, size_t ws_size,
                              hipStream_t stream) {
    const float* x        = (const float*)d_in[0];
    const float* skip     = (const float*)d_in[1];
    const float* offset_w = (const float*)d_in[2];
    const float* offset_b = (const float*)d_in[3];
    const float* deform_w = (const float*)d_in[4];
    float* out  = (float*)d_out;

    float* offs = (float*)d_ws;                          // 9.44 MB
    float* wt2  = offs + OFFS_ELEMS;                     // 46 KB
    unsigned short* wAf = (unsigned short*)(wt2 + WT2_ELEMS);   // 36.9 KB

    hipLaunchKernelGGL(transpose_w_kernel, dim3(8), dim3(256), 0, stream,
                       offset_w, deform_w, wt2, wAf);
    hipLaunchKernelGGL(init_offs_kernel, dim3((OFFS_ELEMS / 4 + 255) / 256), dim3(256),
                       0, stream, offset_b, offs);
    hipLaunchKernelGGL(offset_conv_kernel, dim3(Hn / 4, Bn, CSPLIT), dim3(256),
                       0, stream, x, wt2, offs);
    hipLaunchKernelGGL(deform_kernel, dim3(Hn / ROWS, Bn * NG), dim3(512),
                       0, stream, skip, offs, wAf, out);
}